// Round 2
// baseline (249.289 us; speedup 1.0000x reference)
//
#include <hip/hip_runtime.h>

#define BB 4
#define CC 256
#define HH 96
#define WW 128
#define PP 9
#define OFF 4
#define CCH 16           // channels per LDS chunk
#define NPAIR (CCH / 2)  // 8 f16x2 channel pairs per chunk
#define TPB 288          // 9 dy * 32 pixel-groups

typedef _Float16 h2 __attribute__((ext_vector_type(2)));

__device__ __forceinline__ h2 u2h(unsigned u) { union { unsigned u; h2 h; } x; x.u = u; return x.h; }

#if __has_builtin(__builtin_amdgcn_fdot2)
__device__ __forceinline__ float dot2(h2 a, h2 b, float c) { return __builtin_amdgcn_fdot2(a, b, c, false); }
#else
__device__ __forceinline__ float dot2(h2 a, h2 b, float c) { return c + (float)a[0] * (float)b[0] + (float)a[1] * (float)b[1]; }
#endif

__device__ __forceinline__ unsigned pk(float a, float b) {
#if __has_builtin(__builtin_amdgcn_cvt_pkrtz)
  auto r = __builtin_amdgcn_cvt_pkrtz(a, b);  // __fp16x2 on this clang
  unsigned u;
  __builtin_memcpy(&u, &r, 4);
  return u;
#else
  h2 h; h[0] = (_Float16)a; h[1] = (_Float16)b;
  unsigned u;
  __builtin_memcpy(&u, &h, 4);
  return u;
#endif
}

__global__ __launch_bounds__(TPB, 4) void corr_kernel(const float* __restrict__ in1,
                                                      const float* __restrict__ in2,
                                                      float* __restrict__ out) {
  // in2 halo tile: 8 pairs x 9 rows x (4 pad + 128 + 4 pad) cols of f16x2
  __shared__ unsigned s2[NPAIR][PP][136];  // 39168 B
  __shared__ unsigned s1[NPAIR][WW];       // 4096 B

  // XCD-aware swizzle: assume round-robin blockIdx->XCD; give each XCD a
  // contiguous h-band so the 9x dy re-reads of in2 rows stay in its L2.
  const int bx = blockIdx.x;
  const int xcd = bx & 7;
  const int slot = bx >> 3;          // 0..47
  const int b = slot / 12;           // 0..3
  const int h = xcd * 12 + (slot % 12);  // 0..95

  const int tid = threadIdx.x;
  const int dy = tid >> 5;           // 0..8
  const int pxg = tid & 31;          // 0..31
  const int x0 = pxg << 2;           // 4 consecutive output pixels

  // Zero LDS once: column pads and out-of-range rows stay zero forever
  // (staging below never writes them).
  for (int i = tid; i < NPAIR * PP * 136; i += TPB) ((unsigned*)s2)[i] = 0u;
  __syncthreads();

  float acc[4][PP];
#pragma unroll
  for (int px = 0; px < 4; ++px)
#pragma unroll
    for (int dx = 0; dx < PP; ++dx) acc[px][dx] = 0.f;

  const int plane = HH * WW;         // 12288
  const int base_b = b * CC * plane;

#pragma unroll 1
  for (int c0 = 0; c0 < CC; c0 += CCH) {
    // ---- stage in2 chunk: units (r, p, col-pair): 9*8*64 = 4608 = 16*TPB
#pragma unroll 4
    for (int i = tid; i < PP * NPAIR * 64; i += TPB) {
      const int r = i >> 9;
      const int p = (i >> 6) & 7;
      const int col = (i & 63) << 1;
      const int hr = h + r - OFF;
      if (hr >= 0 && hr < HH) {
        const float* g = in2 + base_b + (c0 + 2 * p) * plane + hr * WW + col;
        const float2 a = *(const float2*)g;
        const float2 c = *(const float2*)(g + plane);  // next channel
        *(uint2*)&s2[p][r][col + 4] = make_uint2(pk(a.x, c.x), pk(a.y, c.y));
      }
    }
    // ---- stage in1 chunk: units (p, col-pair): 8*64 = 512
    for (int i = tid; i < NPAIR * 64; i += TPB) {
      const int p = i >> 6;
      const int col = (i & 63) << 1;
      const float* g = in1 + base_b + (c0 + 2 * p) * plane + h * WW + col;
      const float2 a = *(const float2*)g;
      const float2 c = *(const float2*)(g + plane);
      *(uint2*)&s1[p][col] = make_uint2(pk(a.x, c.x), pk(a.y, c.y));
    }
    __syncthreads();

    // ---- compute: sliding 12-wide f16x2 window, 36 accumulators
#pragma unroll
    for (int p = 0; p < NPAIR; ++p) {
      unsigned q[4];
      unsigned w[12];
      *(uint4*)q = *(const uint4*)&s1[p][x0];
      const uint4* wp = (const uint4*)&s2[p][dy][x0];
      *(uint4*)(w + 0) = wp[0];
      *(uint4*)(w + 4) = wp[1];
      *(uint4*)(w + 8) = wp[2];
#pragma unroll
      for (int px = 0; px < 4; ++px)
#pragma unroll
        for (int dx = 0; dx < PP; ++dx)
          acc[px][dx] = dot2(u2h(w[px + dx]), u2h(q[px]), acc[px][dx]);
    }
    __syncthreads();
  }

  // ---- epilogue: out[((b*81 + dy*9 + dx))*H*W + h*W + x0..x0+3]
  const int ob = (b * PP + dy) * PP * plane + h * WW + x0;
#pragma unroll
  for (int dx = 0; dx < PP; ++dx) {
    const float4 v = make_float4(acc[0][dx], acc[1][dx], acc[2][dx], acc[3][dx]);
    *(float4*)(out + ob + dx * plane) = v;
  }
}

extern "C" void kernel_launch(void* const* d_in, const int* in_sizes, int n_in,
                              void* d_out, int out_size, void* d_ws, size_t ws_size,
                              hipStream_t stream) {
  const float* in1 = (const float*)d_in[0];
  const float* in2 = (const float*)d_in[1];
  float* out = (float*)d_out;
  // 384 blocks = 4 b * 96 h (xcd-swizzled), 288 threads = 9 dy * 32 px-groups
  corr_kernel<<<dim3(BB * HH), dim3(TPB), 0, stream>>>(in1, in2, out);
}